// Round 1
// baseline (88.073 us; speedup 1.0000x reference)
//
#include <hip/hip_runtime.h>
#include <hip/hip_bf16.h>

// Dim indices: N=0, K=1, C=2, P=3, Q=4, R=5, S=6
// DIM_MASK rows  -> Input{N,C,P,Q}=0x1D  Weight{K,C,R,S}=0x66  Output{N,K,P,Q}=0x1B
// REUSE_MASK rows-> Input{K}=0x02        Weight{N,P,Q}=0x19    Output{C,R,S}=0x64

__global__ void hpm_zero(double* __restrict__ ws) {
    if (threadIdx.x < 3) ws[threadIdx.x] = 0.0;
}

__global__ __launch_bounds__(256) void hpm_main(
    const float* __restrict__ T, const float* __restrict__ S,
    const float* __restrict__ PE, const float* __restrict__ BUF,
    double* __restrict__ ws, int G)
{
    const int g = blockIdx.x * 256 + threadIdx.x;

    double lat = 0.0, en = 0.0, mis = 0.0;

    if (g < G) {
        const float pe = PE[0];
        const float sq = sqrtf(pe);
        const float b0 = BUF[0], b1 = BUF[1], b2 = BUF[2];

        const float4* Tp = reinterpret_cast<const float4*>(T) + (size_t)g * 7;
        const float4* Sp = reinterpret_cast<const float4*>(S) + (size_t)g * 7;

        // fp (levels 0,1,2), outer (levels 1,2,3 stored at idx 0,1,2), ru (levels 0,1,2)
        float fpI[3] = {1.f,1.f,1.f}, fpW[3] = {1.f,1.f,1.f}, fpO[3] = {1.f,1.f,1.f};
        float otI[3] = {1.f,1.f,1.f}, otW[3] = {1.f,1.f,1.f}, otO[3] = {1.f,1.f,1.f};
        float ruI[3] = {1.f,1.f,1.f}, ruW[3] = {1.f,1.f,1.f}, ruO[3] = {1.f,1.f,1.f};
        float macs = 1.f;

        constexpr unsigned IN_D = 0x1D, WT_D = 0x66, OU_D = 0x1B;
        constexpr unsigned IN_R = 0x02, WT_R = 0x19, OU_R = 0x64;

        #pragma unroll
        for (int d = 0; d < 7; ++d) {
            const float4 t = Tp[d];
            const float4 s = Sp[d];

            // cumT prefix (levels 0..2)
            const float ct0 = t.x;
            const float ct1 = ct0 * t.y;
            const float ct2 = ct1 * t.z;
            // cumTS prefix (levels 0..3)
            const float u0 = t.x * s.x, u1 = t.y * s.y, u2 = t.z * s.z, u3 = t.w * s.w;
            const float cs0 = u0;
            const float cs1 = cs0 * u1;
            const float cs2 = cs1 * u2;
            const float cs3 = cs2 * u3;
            // sufT suffix (levels 1..3)
            const float st3 = t.w;
            const float st2 = t.z * st3;
            const float st1 = t.y * st2;

            macs *= cs3;

            if ((IN_D >> d) & 1) {
                fpI[0] *= cs0; fpI[1] *= cs1; fpI[2] *= cs2;
                otI[0] *= st1; otI[1] *= st2; otI[2] *= st3;
            }
            if ((WT_D >> d) & 1) {
                fpW[0] *= cs0; fpW[1] *= cs1; fpW[2] *= cs2;
                otW[0] *= st1; otW[1] *= st2; otW[2] *= st3;
            }
            if ((OU_D >> d) & 1) {
                fpO[0] *= cs0; fpO[1] *= cs1; fpO[2] *= cs2;
                otO[0] *= st1; otO[1] *= st2; otO[2] *= st3;
            }
            if ((IN_R >> d) & 1) { ruI[0] *= ct0; ruI[1] *= ct1; ruI[2] *= ct2; }
            if ((WT_R >> d) & 1) { ruW[0] *= ct0; ruW[1] *= ct1; ruW[2] *= ct2; }
            if ((OU_R >> d) & 1) { ruO[0] *= ct0; ruO[1] *= ct1; ruO[2] *= ct2; }
        }

        // acc per interface j: (low,up) = (2,3),(1,2),(0,1); outer idx = up-1
        const float acc0 = 4.f * ( fpI[2] * otI[2] / (ruI[2] + 1e-9f)
                                 + fpW[2] * otW[2] / (ruW[2] + 1e-9f)
                                 + fpO[2] * otO[2] / (ruO[2] + 1e-9f) );
        const float acc1 = 4.f * ( fpI[1] * otI[1] / (ruI[1] + 1e-9f)
                                 + fpW[1] * otW[1] / (ruW[1] + 1e-9f)
                                 + fpO[1] * otO[1] / (ruO[1] + 1e-9f) );
        const float acc2 = 4.f * ( fpI[0] * otI[0] / (ruI[0] + 1e-9f)
                                 + fpW[0] * otW[0] / (ruW[0] + 1e-9f)
                                 + fpO[0] * otO[0] / (ruO[0] + 1e-9f) );

        // latency
        const float bw_dram  = 100.0f * 1e9f + 1e-9f;
        const float bw_onchip = sq * 8e9f + 1e-9f;   // 2*sq*4*1000e6 (GB/s) * 1e9
        const float ml = fmaxf(acc0 / bw_dram,
                               fmaxf(acc1, acc2) / bw_onchip);
        const float cl = macs / (pe * 1e9f + 1e-9f);
        lat = (double)fmaxf(cl, ml);

        // energy
        const float epa0 = 1.2f  + 0.002f * b2;
        const float epa1 = 0.52f + 0.01f  * (b1 / sq);
        const float epa2 = 0.18f;
        en = (double)(macs * 0.56f + (acc0 * epa0 + acc1 * epa1 + acc2 * epa2) * 0.25f);

        // buffer mismatch (levels 0,1,2 vs BUF[0..2])
        const float c = 4.f / 1024.f;
        const float r0 = (fpI[0] + fpW[0] + fpO[0]) * c;
        const float r1 = (fpI[1] + fpW[1] + fpO[1]) * c;
        const float r2 = (fpI[2] + fpW[2] + fpO[2]) * c;
        const float d0 = fmaxf(r0 - b0, 0.f);
        const float d1 = fmaxf(r1 - b1, 0.f);
        const float d2 = fmaxf(r2 - b2, 0.f);
        mis = (double)d0 * d0 + (double)d1 * d1 + (double)d2 * d2;
    }

    // wave (64-lane) shuffle reduction
    #pragma unroll
    for (int off = 32; off > 0; off >>= 1) {
        lat += __shfl_down(lat, off);
        en  += __shfl_down(en,  off);
        mis += __shfl_down(mis, off);
    }

    __shared__ double sred[3][4];
    const int wid  = threadIdx.x >> 6;
    const int lane = threadIdx.x & 63;
    if (lane == 0) { sred[0][wid] = lat; sred[1][wid] = en; sred[2][wid] = mis; }
    __syncthreads();

    if (threadIdx.x == 0) {
        double L = 0.0, E = 0.0, M = 0.0;
        #pragma unroll
        for (int w = 0; w < 4; ++w) { L += sred[0][w]; E += sred[1][w]; M += sred[2][w]; }
        atomicAdd(&ws[0], L);
        atomicAdd(&ws[1], E);
        atomicAdd(&ws[2], M);
    }
}

__global__ void hpm_final(const double* __restrict__ ws,
                          const float* __restrict__ PE,
                          const float* __restrict__ BUF,
                          float* __restrict__ out)
{
    if (threadIdx.x == 0) {
        out[0] = (float)ws[0];                                   // total_latency
        out[1] = (float)ws[1];                                   // total_energy
        out[2] = PE[0] * 0.01f + (BUF[0] + BUF[1] + BUF[2]) * 0.005f; // area
        out[3] = (float)ws[2];                                   // total_mismatch
    }
}

extern "C" void kernel_launch(void* const* d_in, const int* in_sizes, int n_in,
                              void* d_out, int out_size, void* d_ws, size_t ws_size,
                              hipStream_t stream) {
    const float* T   = (const float*)d_in[0];   // temporal_factors [G,7,4]
    const float* S   = (const float*)d_in[1];   // spatial_factors  [G,7,4]
    const float* PE  = (const float*)d_in[2];   // num_pes [1]
    const float* BUF = (const float*)d_in[3];   // buffer_sizes_kb [3]
    float* out = (float*)d_out;
    double* ws = (double*)d_ws;

    const int G = in_sizes[0] / 28;
    const int blocks = (G + 255) / 256;

    hipLaunchKernelGGL(hpm_zero, dim3(1), dim3(64), 0, stream, ws);
    hipLaunchKernelGGL(hpm_main, dim3(blocks), dim3(256), 0, stream, T, S, PE, BUF, ws, G);
    hipLaunchKernelGGL(hpm_final, dim3(1), dim3(64), 0, stream, ws, PE, BUF, out);
}

// Round 2
// 87.856 us; speedup vs baseline: 1.0025x; 1.0025x over previous
//
#include <hip/hip_runtime.h>
#include <hip/hip_bf16.h>

// Dim indices: N=0, K=1, C=2, P=3, Q=4, R=5, S=6
// DIM_MASK rows  -> Input{N,C,P,Q}=0x1D  Weight{K,C,R,S}=0x66  Output{N,K,P,Q}=0x1B
// REUSE_MASK rows-> Input{K}=0x02        Weight{N,P,Q}=0x19    Output{C,R,S}=0x64

typedef const __attribute__((address_space(1))) void* gptr_t;
typedef __attribute__((address_space(3))) void* lptr_t;

__global__ void hpm_zero(double* __restrict__ ws) {
    if (threadIdx.x < 3) ws[threadIdx.x] = 0.0;
}

__global__ __launch_bounds__(256) void hpm_main(
    const float* __restrict__ T, const float* __restrict__ S,
    const float* __restrict__ PE, const float* __restrict__ BUF,
    double* __restrict__ ws, int G)
{
    __shared__ float ldsT[7168];   // 256 groups * 28 floats = 28 KB
    __shared__ float ldsS[7168];   // 28 KB

    const int tid = threadIdx.x;
    const int g0  = blockIdx.x * 256;
    const int g   = g0 + tid;
    const bool full = (g0 + 256 <= G);   // block-uniform

    float4 tv[7], sv[7];
    bool have = false;

    if (full) {
        const int wid = tid >> 6;
        const float* gT = T + (size_t)g0 * 28;
        const float* gS = S + (size_t)g0 * 28;
        #pragma unroll
        for (int k = 0; k < 7; ++k) {
            const int fidx = k * 256 + tid;           // per-lane float4 index in chunk
            const int uoff = (k * 256 + wid * 64) * 4; // wave-uniform LDS float offset
            __builtin_amdgcn_global_load_lds((gptr_t)(gT + (size_t)fidx * 4),
                                             (lptr_t)&ldsT[uoff], 16, 0, 0);
            __builtin_amdgcn_global_load_lds((gptr_t)(gS + (size_t)fidx * 4),
                                             (lptr_t)&ldsS[uoff], 16, 0, 0);
        }
        __syncthreads();   // drains vmcnt before barrier

        const float4* Tl = reinterpret_cast<const float4*>(&ldsT[tid * 28]);
        const float4* Sl = reinterpret_cast<const float4*>(&ldsS[tid * 28]);
        #pragma unroll
        for (int d = 0; d < 7; ++d) { tv[d] = Tl[d]; sv[d] = Sl[d]; }
        have = true;
    } else if (g < G) {
        const float4* Tp = reinterpret_cast<const float4*>(T) + (size_t)g * 7;
        const float4* Sp = reinterpret_cast<const float4*>(S) + (size_t)g * 7;
        #pragma unroll
        for (int d = 0; d < 7; ++d) { tv[d] = Tp[d]; sv[d] = Sp[d]; }
        have = true;
    }

    double lat = 0.0, en = 0.0, mis = 0.0;

    if (have) {
        const float pe = PE[0];
        const float sq = sqrtf(pe);
        const float b0 = BUF[0], b1 = BUF[1], b2 = BUF[2];

        float fpI[3] = {1.f,1.f,1.f}, fpW[3] = {1.f,1.f,1.f}, fpO[3] = {1.f,1.f,1.f};
        float otI[3] = {1.f,1.f,1.f}, otW[3] = {1.f,1.f,1.f}, otO[3] = {1.f,1.f,1.f};
        float ruI[3] = {1.f,1.f,1.f}, ruW[3] = {1.f,1.f,1.f}, ruO[3] = {1.f,1.f,1.f};
        float macs = 1.f;

        constexpr unsigned IN_D = 0x1D, WT_D = 0x66, OU_D = 0x1B;
        constexpr unsigned IN_R = 0x02, WT_R = 0x19, OU_R = 0x64;

        #pragma unroll
        for (int d = 0; d < 7; ++d) {
            const float4 t = tv[d];
            const float4 s = sv[d];

            const float ct0 = t.x;
            const float ct1 = ct0 * t.y;
            const float ct2 = ct1 * t.z;
            const float u0 = t.x * s.x, u1 = t.y * s.y, u2 = t.z * s.z, u3 = t.w * s.w;
            const float cs0 = u0;
            const float cs1 = cs0 * u1;
            const float cs2 = cs1 * u2;
            const float cs3 = cs2 * u3;
            const float st3 = t.w;
            const float st2 = t.z * st3;
            const float st1 = t.y * st2;

            macs *= cs3;

            if ((IN_D >> d) & 1) {
                fpI[0] *= cs0; fpI[1] *= cs1; fpI[2] *= cs2;
                otI[0] *= st1; otI[1] *= st2; otI[2] *= st3;
            }
            if ((WT_D >> d) & 1) {
                fpW[0] *= cs0; fpW[1] *= cs1; fpW[2] *= cs2;
                otW[0] *= st1; otW[1] *= st2; otW[2] *= st3;
            }
            if ((OU_D >> d) & 1) {
                fpO[0] *= cs0; fpO[1] *= cs1; fpO[2] *= cs2;
                otO[0] *= st1; otO[1] *= st2; otO[2] *= st3;
            }
            if ((IN_R >> d) & 1) { ruI[0] *= ct0; ruI[1] *= ct1; ruI[2] *= ct2; }
            if ((WT_R >> d) & 1) { ruW[0] *= ct0; ruW[1] *= ct1; ruW[2] *= ct2; }
            if ((OU_R >> d) & 1) { ruO[0] *= ct0; ruO[1] *= ct1; ruO[2] *= ct2; }
        }

        const float acc0 = 4.f * ( fpI[2] * otI[2] / (ruI[2] + 1e-9f)
                                 + fpW[2] * otW[2] / (ruW[2] + 1e-9f)
                                 + fpO[2] * otO[2] / (ruO[2] + 1e-9f) );
        const float acc1 = 4.f * ( fpI[1] * otI[1] / (ruI[1] + 1e-9f)
                                 + fpW[1] * otW[1] / (ruW[1] + 1e-9f)
                                 + fpO[1] * otO[1] / (ruO[1] + 1e-9f) );
        const float acc2 = 4.f * ( fpI[0] * otI[0] / (ruI[0] + 1e-9f)
                                 + fpW[0] * otW[0] / (ruW[0] + 1e-9f)
                                 + fpO[0] * otO[0] / (ruO[0] + 1e-9f) );

        const float bw_dram   = 100.0f * 1e9f + 1e-9f;
        const float bw_onchip = sq * 8e9f + 1e-9f;   // 2*sq*4B*1000MHz in B/s
        const float ml = fmaxf(acc0 / bw_dram,
                               fmaxf(acc1, acc2) / bw_onchip);
        const float cl = macs / (pe * 1e9f + 1e-9f);
        lat = (double)fmaxf(cl, ml);

        const float epa0 = 1.2f  + 0.002f * b2;
        const float epa1 = 0.52f + 0.01f  * (b1 / sq);
        const float epa2 = 0.18f;
        en = (double)(macs * 0.56f + (acc0 * epa0 + acc1 * epa1 + acc2 * epa2) * 0.25f);

        const float c = 4.f / 1024.f;
        const float r0 = (fpI[0] + fpW[0] + fpO[0]) * c;
        const float r1 = (fpI[1] + fpW[1] + fpO[1]) * c;
        const float r2 = (fpI[2] + fpW[2] + fpO[2]) * c;
        const float d0 = fmaxf(r0 - b0, 0.f);
        const float d1 = fmaxf(r1 - b1, 0.f);
        const float d2 = fmaxf(r2 - b2, 0.f);
        mis = (double)d0 * d0 + (double)d1 * d1 + (double)d2 * d2;
    }

    // wave (64-lane) shuffle reduction
    #pragma unroll
    for (int off = 32; off > 0; off >>= 1) {
        lat += __shfl_down(lat, off);
        en  += __shfl_down(en,  off);
        mis += __shfl_down(mis, off);
    }

    __shared__ double sred[3][4];
    const int wid  = threadIdx.x >> 6;
    const int lane = threadIdx.x & 63;
    if (lane == 0) { sred[0][wid] = lat; sred[1][wid] = en; sred[2][wid] = mis; }
    __syncthreads();

    if (threadIdx.x == 0) {
        double L = 0.0, E = 0.0, M = 0.0;
        #pragma unroll
        for (int w = 0; w < 4; ++w) { L += sred[0][w]; E += sred[1][w]; M += sred[2][w]; }
        atomicAdd(&ws[0], L);
        atomicAdd(&ws[1], E);
        atomicAdd(&ws[2], M);
    }
}

__global__ void hpm_final(const double* __restrict__ ws,
                          const float* __restrict__ PE,
                          const float* __restrict__ BUF,
                          float* __restrict__ out)
{
    if (threadIdx.x == 0) {
        out[0] = (float)ws[0];                                   // total_latency
        out[1] = (float)ws[1];                                   // total_energy
        out[2] = PE[0] * 0.01f + (BUF[0] + BUF[1] + BUF[2]) * 0.005f; // area
        out[3] = (float)ws[2];                                   // total_mismatch
    }
}

extern "C" void kernel_launch(void* const* d_in, const int* in_sizes, int n_in,
                              void* d_out, int out_size, void* d_ws, size_t ws_size,
                              hipStream_t stream) {
    const float* T   = (const float*)d_in[0];   // temporal_factors [G,7,4]
    const float* S   = (const float*)d_in[1];   // spatial_factors  [G,7,4]
    const float* PE  = (const float*)d_in[2];   // num_pes [1]
    const float* BUF = (const float*)d_in[3];   // buffer_sizes_kb [3]
    float* out = (float*)d_out;
    double* ws = (double*)d_ws;

    const int G = in_sizes[0] / 28;
    const int blocks = (G + 255) / 256;

    hipLaunchKernelGGL(hpm_zero, dim3(1), dim3(64), 0, stream, ws);
    hipLaunchKernelGGL(hpm_main, dim3(blocks), dim3(256), 0, stream, T, S, PE, BUF, ws, G);
    hipLaunchKernelGGL(hpm_final, dim3(1), dim3(64), 0, stream, ws, PE, BUF, out);
}

// Round 3
// 28.277 us; speedup vs baseline: 3.1146x; 3.1069x over previous
//
#include <hip/hip_runtime.h>
#include <hip/hip_bf16.h>

// Dim indices: N=0, K=1, C=2, P=3, Q=4, R=5, S=6
// DIM_MASK rows  -> Input{N,C,P,Q}=0x1D  Weight{K,C,R,S}=0x66  Output{N,K,P,Q}=0x1B
// REUSE_MASK rows-> Input{K}=0x02        Weight{N,P,Q}=0x19    Output{C,R,S}=0x64

typedef const __attribute__((address_space(1))) void* gptr_t;
typedef __attribute__((address_space(3))) void* lptr_t;

__global__ __launch_bounds__(256) void hpm_main(
    const float* __restrict__ T, const float* __restrict__ S,
    const float* __restrict__ PE, const float* __restrict__ BUF,
    double* __restrict__ part, int G, int NB)
{
    __shared__ float ldsT[7168];   // 256 groups * 28 floats = 28 KB
    __shared__ float ldsS[7168];   // 28 KB

    const int tid = threadIdx.x;
    const int g0  = blockIdx.x * 256;
    const int g   = g0 + tid;
    const bool full = (g0 + 256 <= G);   // block-uniform

    float4 tv[7], sv[7];
    bool have = false;

    if (full) {
        const int wid = tid >> 6;
        const float* gT = T + (size_t)g0 * 28;
        const float* gS = S + (size_t)g0 * 28;
        #pragma unroll
        for (int k = 0; k < 7; ++k) {
            const int fidx = k * 256 + tid;            // per-lane float4 index in chunk
            const int uoff = (k * 256 + wid * 64) * 4; // wave-uniform LDS float offset
            __builtin_amdgcn_global_load_lds((gptr_t)(gT + (size_t)fidx * 4),
                                             (lptr_t)&ldsT[uoff], 16, 0, 0);
            __builtin_amdgcn_global_load_lds((gptr_t)(gS + (size_t)fidx * 4),
                                             (lptr_t)&ldsS[uoff], 16, 0, 0);
        }
        __syncthreads();   // drains vmcnt before barrier

        const float4* Tl = reinterpret_cast<const float4*>(&ldsT[tid * 28]);
        const float4* Sl = reinterpret_cast<const float4*>(&ldsS[tid * 28]);
        #pragma unroll
        for (int d = 0; d < 7; ++d) { tv[d] = Tl[d]; sv[d] = Sl[d]; }
        have = true;
    } else if (g < G) {
        const float4* Tp = reinterpret_cast<const float4*>(T) + (size_t)g * 7;
        const float4* Sp = reinterpret_cast<const float4*>(S) + (size_t)g * 7;
        #pragma unroll
        for (int d = 0; d < 7; ++d) { tv[d] = Tp[d]; sv[d] = Sp[d]; }
        have = true;
    }

    double lat = 0.0, en = 0.0, mis = 0.0;

    if (have) {
        const float pe = PE[0];
        const float sq = sqrtf(pe);
        const float b0 = BUF[0], b1 = BUF[1], b2 = BUF[2];

        float fpI[3] = {1.f,1.f,1.f}, fpW[3] = {1.f,1.f,1.f}, fpO[3] = {1.f,1.f,1.f};
        float otI[3] = {1.f,1.f,1.f}, otW[3] = {1.f,1.f,1.f}, otO[3] = {1.f,1.f,1.f};
        float ruI[3] = {1.f,1.f,1.f}, ruW[3] = {1.f,1.f,1.f}, ruO[3] = {1.f,1.f,1.f};
        float macs = 1.f;

        constexpr unsigned IN_D = 0x1D, WT_D = 0x66, OU_D = 0x1B;
        constexpr unsigned IN_R = 0x02, WT_R = 0x19, OU_R = 0x64;

        #pragma unroll
        for (int d = 0; d < 7; ++d) {
            const float4 t = tv[d];
            const float4 s = sv[d];

            const float ct0 = t.x;
            const float ct1 = ct0 * t.y;
            const float ct2 = ct1 * t.z;
            const float u0 = t.x * s.x, u1 = t.y * s.y, u2 = t.z * s.z, u3 = t.w * s.w;
            const float cs0 = u0;
            const float cs1 = cs0 * u1;
            const float cs2 = cs1 * u2;
            const float cs3 = cs2 * u3;
            const float st3 = t.w;
            const float st2 = t.z * st3;
            const float st1 = t.y * st2;

            macs *= cs3;

            if ((IN_D >> d) & 1) {
                fpI[0] *= cs0; fpI[1] *= cs1; fpI[2] *= cs2;
                otI[0] *= st1; otI[1] *= st2; otI[2] *= st3;
            }
            if ((WT_D >> d) & 1) {
                fpW[0] *= cs0; fpW[1] *= cs1; fpW[2] *= cs2;
                otW[0] *= st1; otW[1] *= st2; otW[2] *= st3;
            }
            if ((OU_D >> d) & 1) {
                fpO[0] *= cs0; fpO[1] *= cs1; fpO[2] *= cs2;
                otO[0] *= st1; otO[1] *= st2; otO[2] *= st3;
            }
            if ((IN_R >> d) & 1) { ruI[0] *= ct0; ruI[1] *= ct1; ruI[2] *= ct2; }
            if ((WT_R >> d) & 1) { ruW[0] *= ct0; ruW[1] *= ct1; ruW[2] *= ct2; }
            if ((OU_R >> d) & 1) { ruO[0] *= ct0; ruO[1] *= ct1; ruO[2] *= ct2; }
        }

        const float acc0 = 4.f * ( fpI[2] * otI[2] / (ruI[2] + 1e-9f)
                                 + fpW[2] * otW[2] / (ruW[2] + 1e-9f)
                                 + fpO[2] * otO[2] / (ruO[2] + 1e-9f) );
        const float acc1 = 4.f * ( fpI[1] * otI[1] / (ruI[1] + 1e-9f)
                                 + fpW[1] * otW[1] / (ruW[1] + 1e-9f)
                                 + fpO[1] * otO[1] / (ruO[1] + 1e-9f) );
        const float acc2 = 4.f * ( fpI[0] * otI[0] / (ruI[0] + 1e-9f)
                                 + fpW[0] * otW[0] / (ruW[0] + 1e-9f)
                                 + fpO[0] * otO[0] / (ruO[0] + 1e-9f) );

        const float bw_dram   = 100.0f * 1e9f + 1e-9f;
        const float bw_onchip = sq * 8e9f + 1e-9f;   // 2*sq*4B*1000MHz in B/s
        const float ml = fmaxf(acc0 / bw_dram,
                               fmaxf(acc1, acc2) / bw_onchip);
        const float cl = macs / (pe * 1e9f + 1e-9f);
        lat = (double)fmaxf(cl, ml);

        const float epa0 = 1.2f  + 0.002f * b2;
        const float epa1 = 0.52f + 0.01f  * (b1 / sq);
        const float epa2 = 0.18f;
        en = (double)(macs * 0.56f + (acc0 * epa0 + acc1 * epa1 + acc2 * epa2) * 0.25f);

        const float c = 4.f / 1024.f;
        const float r0 = (fpI[0] + fpW[0] + fpO[0]) * c;
        const float r1 = (fpI[1] + fpW[1] + fpO[1]) * c;
        const float r2 = (fpI[2] + fpW[2] + fpO[2]) * c;
        const float d0 = fmaxf(r0 - b0, 0.f);
        const float d1 = fmaxf(r1 - b1, 0.f);
        const float d2 = fmaxf(r2 - b2, 0.f);
        mis = (double)d0 * d0 + (double)d1 * d1 + (double)d2 * d2;
    }

    // wave (64-lane) shuffle reduction
    #pragma unroll
    for (int off = 32; off > 0; off >>= 1) {
        lat += __shfl_down(lat, off);
        en  += __shfl_down(en,  off);
        mis += __shfl_down(mis, off);
    }

    __shared__ double sred[3][4];
    const int wid  = threadIdx.x >> 6;
    const int lane = threadIdx.x & 63;
    if (lane == 0) { sred[0][wid] = lat; sred[1][wid] = en; sred[2][wid] = mis; }
    __syncthreads();

    if (threadIdx.x == 0) {
        double L = 0.0, E = 0.0, M = 0.0;
        #pragma unroll
        for (int w = 0; w < 4; ++w) { L += sred[0][w]; E += sred[1][w]; M += sred[2][w]; }
        // private per-block slots, plane-major for coalesced reduction reads
        part[0 * NB + blockIdx.x] = L;
        part[1 * NB + blockIdx.x] = E;
        part[2 * NB + blockIdx.x] = M;
    }
}

__global__ __launch_bounds__(256) void hpm_final(
    const double* __restrict__ part, int NB,
    const float* __restrict__ PE, const float* __restrict__ BUF,
    float* __restrict__ out)
{
    const int tid = threadIdx.x;
    double L = 0.0, E = 0.0, M = 0.0;
    for (int i = tid; i < NB; i += 256) {
        L += part[0 * NB + i];
        E += part[1 * NB + i];
        M += part[2 * NB + i];
    }

    #pragma unroll
    for (int off = 32; off > 0; off >>= 1) {
        L += __shfl_down(L, off);
        E += __shfl_down(E, off);
        M += __shfl_down(M, off);
    }

    __shared__ double sred[3][4];
    const int wid  = tid >> 6;
    const int lane = tid & 63;
    if (lane == 0) { sred[0][wid] = L; sred[1][wid] = E; sred[2][wid] = M; }
    __syncthreads();

    if (tid == 0) {
        double Lt = 0.0, Et = 0.0, Mt = 0.0;
        #pragma unroll
        for (int w = 0; w < 4; ++w) { Lt += sred[0][w]; Et += sred[1][w]; Mt += sred[2][w]; }
        out[0] = (float)Lt;                                           // total_latency
        out[1] = (float)Et;                                           // total_energy
        out[2] = PE[0] * 0.01f + (BUF[0] + BUF[1] + BUF[2]) * 0.005f; // area
        out[3] = (float)Mt;                                           // total_mismatch
    }
}

extern "C" void kernel_launch(void* const* d_in, const int* in_sizes, int n_in,
                              void* d_out, int out_size, void* d_ws, size_t ws_size,
                              hipStream_t stream) {
    const float* T   = (const float*)d_in[0];   // temporal_factors [G,7,4]
    const float* S   = (const float*)d_in[1];   // spatial_factors  [G,7,4]
    const float* PE  = (const float*)d_in[2];   // num_pes [1]
    const float* BUF = (const float*)d_in[3];   // buffer_sizes_kb [3]
    float* out = (float*)d_out;
    double* ws = (double*)d_ws;

    const int G = in_sizes[0] / 28;
    const int blocks = (G + 255) / 256;   // NB partial slots per plane

    hipLaunchKernelGGL(hpm_main, dim3(blocks), dim3(256), 0, stream,
                       T, S, PE, BUF, ws, G, blocks);
    hipLaunchKernelGGL(hpm_final, dim3(1), dim3(256), 0, stream,
                       ws, blocks, PE, BUF, out);
}